// Round 15
// baseline (188.294 us; speedup 1.0000x reference)
//
#include <hip/hip_runtime.h>
#include <stdint.h>

#define TOKENS 8192
#define IN_F   4096
#define OUT_F  4096
#define THREADS 512

typedef int v4i __attribute__((ext_vector_type(4)));

#define GLOBAL_AS __attribute__((address_space(1)))
#define LDS_AS    __attribute__((address_space(3)))

// ---- fused pack: x int32->int8, W int32 [K][N] -> int8 WT [N][K] ----
#define XBLOCKS (TOKENS * IN_F / 4 / 256)   // 8192
__global__ __launch_bounds__(256) void pack_kernel(const int* __restrict__ x32,
                                                   uint8_t* __restrict__ x8,
                                                   const int* __restrict__ w32,
                                                   uint8_t* __restrict__ wt8) {
  if (blockIdx.x < XBLOCKS) {
    int t = blockIdx.x * 256 + threadIdx.x;
    const int4 v = ((const int4*)x32)[t];
    uint32_t p = (uint32_t)(v.x & 0xFF)
               | ((uint32_t)(v.y & 0xFF) << 8)
               | ((uint32_t)(v.z & 0xFF) << 16)
               | ((uint32_t)(v.w & 0xFF) << 24);
    ((uint32_t*)x8)[t] = p;
  } else {
    int b = blockIdx.x - XBLOCKS;
    int tn = (b & 63) * 64;
    int tk = (b >> 6) * 64;
    int t = threadIdx.x;
    int n  = tn + (t >> 2);
    int k0 = tk + (t & 3) * 16;
    uint32_t words[4];
#pragma unroll
    for (int w = 0; w < 4; ++w) {
      uint32_t acc = 0;
#pragma unroll
      for (int j = 0; j < 4; ++j) {
        int val = w32[(size_t)(k0 + w * 4 + j) * OUT_F + n];
        acc |= (uint32_t)(val & 0xFF) << (8 * j);
      }
      words[w] = acc;
    }
    uint4 o = make_uint4(words[0], words[1], words[2], words[3]);
    *(uint4*)(wt8 + (size_t)n * IN_F + k0) = o;
  }
}

// ---- int8 GEMM: 256x256, 8 waves (128x64/wave), faithful 8-phase schedule ----
// See FIFO/hazard audit in the round's theory: vmcnt(8)+barrier at even-phase
// tails drains exactly the two half-tiles read two phases later; every staged
// region's last readers are >=1 barrier in the past. Never vmcnt(0) mid-loop.
__global__ __launch_bounds__(THREADS, 2) void gemm_i8_kernel(const uint8_t* __restrict__ A,
                                                             const uint8_t* __restrict__ BT,
                                                             const int* __restrict__ bias,
                                                             const float* __restrict__ scales,
                                                             int* __restrict__ out) {
  __shared__ __align__(16) uint8_t lds[131072];   // buf0 @0, buf1 @65536; B at +32768

  const int t    = threadIdx.x;
  const int lane = t & 63;
  const int w    = t >> 6;     // 0..7
  const int wr   = w >> 2;     // 0..1
  const int wc   = w & 3;      // 0..3
  const int fr   = lane & 15;
  const int fq   = lane >> 4;

  // XCD-aware bijective swizzle: 512 blocks, 512 % 8 == 0
  int bid = blockIdx.x;
  int swz = (bid & 7) * 64 + (bid >> 3);
  int bm = swz >> 4;           // 0..31
  int bn = swz & 15;           // 0..15

  // staging: pre-swizzled global source, linear LDS dest (rule #21).
  // sigma(l)=l^((l>>3)&7) on 16B chunks per 8-KiB half (0-conflict R3-R14).
  const int lsz  = t ^ ((t >> 3) & 7);
  const int srow = lsz >> 2;            // 0..127
  const int scol = (lsz & 3) * 16;
  const uint8_t* GA = A  + (size_t)(bm * 256 + srow) * IN_F + scol;
  const uint8_t* GB = BT + (size_t)(bn * 256 + srow) * IN_F + scol;

  auto stg = [&](int buf, int isB, int pan, int kt) {
    const uint8_t* G = isB ? GB : GA;
    uint8_t* d = lds + buf * 65536 + isB * 32768 + pan * 16384 + t * 16;
    const uint8_t* s = G + (size_t)kt * 128 + pan * 64;
    __builtin_amdgcn_global_load_lds((const GLOBAL_AS void*)s,
                                     (LDS_AS void*)d, 16, 0, 0);
    __builtin_amdgcn_global_load_lds((const GLOBAL_AS void*)(s + (size_t)128 * IN_F),
                                     (LDS_AS void*)(d + 8192), 16, 0, 0);
  };

  // fragment bases (sigma term frag-index invariant: ((rl>>1)&7) == (fr>>1)&7)
  const int sig   = ((fr >> 1) & 7) << 4;
  const int abase = wr * 8192 + ((fr * 64 + fq * 16) ^ sig);
  const int bbase = 32768 + (wc >> 1) * 8192 + ((((wc & 1) * 64 + fr) * 64 + fq * 16) ^ sig);

  v4i acc[8][4];
  const v4i vz = {0, 0, 0, 0};
#pragma unroll
  for (int m = 0; m < 8; ++m)
#pragma unroll
    for (int n = 0; n < 4; ++n) acc[m][n] = vz;

#define VMB(N) asm volatile("s_waitcnt vmcnt(" #N ")" ::: "memory"); \
               asm volatile("s_barrier" ::: "memory");
#define BARO   asm volatile("s_barrier" ::: "memory");

#define PHASE(buf, pan, mh, RDBF, STG_STMT)                                     \
  {                                                                             \
    const uint8_t* cb = lds + (buf) * 65536 + (pan) * 16384;                    \
    if (RDBF) {                                                                 \
      _Pragma("unroll") for (int n = 0; n < 4; ++n)                             \
        bf[n] = *(const v4i*)(cb + bbase + n * 1024);                           \
    }                                                                           \
    v4i af[4];                                                                  \
    _Pragma("unroll") for (int mm = 0; mm < 4; ++mm)                            \
      af[mm] = *(const v4i*)(cb + abase + (mh) * 4096 + mm * 1024);             \
    STG_STMT;                                                                   \
    __builtin_amdgcn_s_setprio(1);                                              \
    _Pragma("unroll") for (int mm = 0; mm < 4; ++mm)                            \
      _Pragma("unroll") for (int n = 0; n < 4; ++n)                             \
        acc[(mh) * 4 + mm][n] = __builtin_amdgcn_mfma_i32_16x16x64_i8(          \
            af[mm], bf[n], acc[(mh) * 4 + mm][n], 0, 0, 0);                     \
    __builtin_amdgcn_s_setprio(0);                                              \
  }

  // Prologue: buf0.{Ap0,Bp0,Ap1,Bp1}(kt0), buf1.{Ap0,Bp0}(kt1) = 12 loads.
  stg(0, 0, 0, 0); stg(0, 1, 0, 0); stg(0, 0, 1, 0); stg(0, 1, 1, 0);
  stg(1, 0, 0, 1); stg(1, 1, 0, 1);
  VMB(8)   // drains buf0.Ap0,Bp0 -> ph1/2 of iter 0 safe

  for (int it = 0; it < 15; ++it) {
    const int t1 = 2 * it + 1, tn0 = 2 * it + 2, tn1 = 2 * it + 3;
    v4i bf[4];
    PHASE(0, 0, 0, true,  stg(1, 0, 1, t1))   BARO      // ph1
    PHASE(0, 0, 1, false, stg(1, 1, 1, t1))   VMB(8)    // ph2
    PHASE(0, 1, 0, true,  stg(0, 0, 0, tn0))  BARO      // ph3
    PHASE(0, 1, 1, false, stg(0, 1, 0, tn0))  VMB(8)    // ph4
    PHASE(1, 0, 0, true,  stg(0, 0, 1, tn0))  BARO      // ph5
    PHASE(1, 0, 1, false, stg(0, 1, 1, tn0))  VMB(8)    // ph6
    PHASE(1, 1, 0, true,  stg(1, 0, 0, tn1))  BARO      // ph7
    PHASE(1, 1, 1, false, stg(1, 1, 0, tn1))  VMB(8)    // ph8
  }
  {
    // iter 15 (K-tiles 30,31): stage only buf1.Ap1/Bp1; drain 8->4->0.
    v4i bf[4];
    PHASE(0, 0, 0, true,  stg(1, 0, 1, 31))   BARO
    PHASE(0, 0, 1, false, stg(1, 1, 1, 31))   VMB(8)
    PHASE(0, 1, 0, true,  )                   BARO
    PHASE(0, 1, 1, false, )                   VMB(4)
    PHASE(1, 0, 0, true,  )                   BARO
    PHASE(1, 0, 1, false, )                   VMB(0)
    PHASE(1, 1, 0, true,  )                   BARO
    PHASE(1, 1, 1, false, )
  }
#undef PHASE
#undef VMB
#undef BARO

  // ---- epilogue: (acc + bias) * scale * 20, clip, trunc; int32 out ----
  // C/D layout (16x16): col = lane&15, row = (lane>>4)*4 + r
#pragma unroll
  for (int n = 0; n < 4; ++n) {
    const int gn  = bn * 256 + wc * 64 + n * 16 + fr;
    const int bsv = bias[gn];
    const float sc = scales[gn] * 20.0f;
#pragma unroll
    for (int m = 0; m < 8; ++m) {
      const int gm0 = bm * 256 + wr * 128 + m * 16 + fq * 4;
#pragma unroll
      for (int r = 0; r < 4; ++r) {
        float g = (float)(acc[m][n][r] + bsv) * sc;
        g = fminf(fmaxf(g, -128.0f), 127.0f);
        out[(size_t)(gm0 + r) * OUT_F + gn] = (int)g;
      }
    }
  }
}

extern "C" void kernel_launch(void* const* d_in, const int* in_sizes, int n_in,
                              void* d_out, int out_size, void* d_ws, size_t ws_size,
                              hipStream_t stream) {
  const int*   x32    = (const int*)d_in[0];
  const int*   w32    = (const int*)d_in[1];
  const int*   bias   = (const int*)d_in[2];
  const float* scales = (const float*)d_in[3];
  int* out = (int*)d_out;

  uint8_t* x8  = (uint8_t*)d_ws;                              // 32 MB
  uint8_t* wt8 = (uint8_t*)d_ws + (size_t)TOKENS * IN_F;      // 16 MB

  pack_kernel<<<XBLOCKS + (OUT_F / 64) * (IN_F / 64), 256, 0, stream>>>(x32, x8, w32, wt8);
  gemm_i8_kernel<<<(TOKENS / 256) * (OUT_F / 256), THREADS, 0, stream>>>(x8, wt8, bias, scales, out);
}